// Round 1
// baseline (295.198 us; speedup 1.0000x reference)
//
#include <hip/hip_runtime.h>

typedef _Float16 f16;
typedef f16 f16x8 __attribute__((ext_vector_type(8)));
typedef float f32x4 __attribute__((ext_vector_type(4)));
typedef unsigned int u32;
typedef unsigned long long u64;

#define DEV static __device__ __forceinline__

// Problem constants: B=2, S=2048, D=1024, H=16, HD=64
#define S_ 2048
#define D_ 1024

// ---------------- helpers ----------------
// XOR swizzle for 32-elem (64B) rows: 4 chunks of 8 f16 (16B)
DEV int swz32(int row, int chunk) { return row * 32 + (((chunk ^ row) & 3) << 3); }
// XOR swizzle for 64-elem (128B) rows: 8 chunks of 8 f16 (16B)
DEV int swz64(int row, int chunk) { return row * 64 + (((chunk ^ row) & 7) << 3); }
// element-granular address into swizzled 64-elem rows
DEV int swz64e(int row, int col) {
    return row * 64 + ((((col >> 3) ^ row) & 7) << 3) + (col & 7);
}

// ---------------- fp32 -> fp16 convert (x, W_attn, W_proj) ----------------
__global__ void convert_f16(const float* __restrict__ x, const float* __restrict__ wa,
                            const float* __restrict__ wp,
                            f16* __restrict__ xb, f16* __restrict__ wab, f16* __restrict__ wpb) {
    u32 t = blockIdx.x * blockDim.x + threadIdx.x;
    u32 base = t * 8u;                    // 8,388,608 total elems
    const float* src; f16* dst; u32 off;
    if (base < 4194304u)      { src = x;  dst = xb;  off = base; }
    else if (base < 7340032u) { src = wa; dst = wab; off = base - 4194304u; }
    else                      { src = wp; dst = wpb; off = base - 7340032u; }
    float4 a = *(const float4*)(src + off);
    float4 b = *(const float4*)(src + off + 4);
    f16x8 v;
    v[0] = (f16)a.x; v[1] = (f16)a.y; v[2] = (f16)a.z; v[3] = (f16)a.w;
    v[4] = (f16)b.x; v[5] = (f16)b.y; v[6] = (f16)b.z; v[7] = (f16)b.w;
    *(f16x8*)(dst + off) = v;
}

// ---------------- GEMM (A[M][K] * Bt[N][K]^T), 128x128 tile, BK=32 ----------------
// EPI==0: QKV epilogue -> scatter q(*0.125)/k/v into [B][H][S][HD] f16
// EPI==1: proj epilogue -> fp32 out + bias
template <int EPI>
__global__ __launch_bounds__(256) void gemm_bt(
    const f16* __restrict__ A, const f16* __restrict__ Bt, int K,
    f16* __restrict__ oQ, f16* __restrict__ oK, f16* __restrict__ oV,
    float* __restrict__ oY, const float* __restrict__ bias) {
    __shared__ f16 As[4096];
    __shared__ f16 Bs[4096];
    const int tid = threadIdx.x;
    const int lane = tid & 63;
    const int la = lane & 15, lg = lane >> 4;
    const int wv = tid >> 6;
    const int wr = (wv >> 1) << 6, wc = (wv & 1) << 6;
    const int r0 = blockIdx.x << 7, c0 = blockIdx.y << 7;

    const f32x4 VZ = {0.f, 0.f, 0.f, 0.f};
    f32x4 acc[4][4];
#pragma unroll
    for (int m = 0; m < 4; ++m)
#pragma unroll
        for (int n = 0; n < 4; ++n) acc[m][n] = VZ;

    const u32 f0 = tid * 8u, f1 = f0 + 2048u;
    const int ar0 = f0 >> 5, ac0 = f0 & 31;
    const int ar1 = f1 >> 5, ac1 = f1 & 31;
    const f16* Ab = A + (u64)r0 * K;
    const f16* Bb = Bt + (u64)c0 * K;

    for (int k0 = 0; k0 < K; k0 += 32) {
        // prefetch to regs (overlaps previous tile's compute)
        f16x8 va0 = *(const f16x8*)(Ab + (u64)ar0 * K + k0 + ac0);
        f16x8 va1 = *(const f16x8*)(Ab + (u64)ar1 * K + k0 + ac1);
        f16x8 vb0 = *(const f16x8*)(Bb + (u64)ar0 * K + k0 + ac0);
        f16x8 vb1 = *(const f16x8*)(Bb + (u64)ar1 * K + k0 + ac1);
        __syncthreads();
        *(f16x8*)(As + swz32(ar0, ac0 >> 3)) = va0;
        *(f16x8*)(As + swz32(ar1, ac1 >> 3)) = va1;
        *(f16x8*)(Bs + swz32(ar0, ac0 >> 3)) = vb0;
        *(f16x8*)(Bs + swz32(ar1, ac1 >> 3)) = vb1;
        __syncthreads();
        f16x8 af[4], bf[4];
#pragma unroll
        for (int m = 0; m < 4; ++m) af[m] = *(const f16x8*)(As + swz32(wr + m * 16 + la, lg));
#pragma unroll
        for (int n = 0; n < 4; ++n) bf[n] = *(const f16x8*)(Bs + swz32(wc + n * 16 + la, lg));
#pragma unroll
        for (int m = 0; m < 4; ++m)
#pragma unroll
            for (int n = 0; n < 4; ++n)
                acc[m][n] = __builtin_amdgcn_mfma_f32_16x16x32_f16(af[m], bf[n], acc[m][n], 0, 0, 0);
    }

    if (EPI == 0) {
#pragma unroll
        for (int n = 0; n < 4; ++n) {
            int col = c0 + wc + n * 16 + la;   // 0..3071
            f16* dst; int d; float sc;
            if (col < 1024)      { dst = oQ; d = col;        sc = 0.125f; }
            else if (col < 2048) { dst = oK; d = col - 1024; sc = 1.0f; }
            else                 { dst = oV; d = col - 2048; sc = 1.0f; }
            int h = d >> 6, hd = d & 63;
#pragma unroll
            for (int m = 0; m < 4; ++m) {
#pragma unroll
                for (int j = 0; j < 4; ++j) {
                    int row = r0 + wr + m * 16 + lg * 4 + j;  // 0..4095
                    int b = row >> 11, s = row & 2047;
                    u64 idx = (((u64)(b * 16 + h)) * 2048 + s) * 64 + hd;
                    dst[idx] = (f16)(acc[m][n][j] * sc);
                }
            }
        }
    } else {
#pragma unroll
        for (int n = 0; n < 4; ++n) {
            int col = c0 + wc + n * 16 + la;
            float bv = bias[col];
#pragma unroll
            for (int m = 0; m < 4; ++m)
#pragma unroll
                for (int j = 0; j < 4; ++j) {
                    int row = r0 + wr + m * 16 + lg * 4 + j;
                    oY[(u64)row * 1024 + col] = acc[m][n][j] + bv;
                }
        }
    }
}

// ---------------- fused attention ----------------
// grid: (32 q-tiles, 32 b*h). block: 256 (4 waves). Each wave owns 16 q-rows.
// pass 1: rowsum of exp(scores) (q pre-scaled by 1/8). pass 2: recompute scores,
// write att = exp(s)*invl (fp32, d_out), fuse PV via LDS P-tile, write ya (f16).
__global__ __launch_bounds__(256) void attn_fused(
    const f16* __restrict__ q, const f16* __restrict__ k, const f16* __restrict__ v,
    float* __restrict__ att, f16* __restrict__ ya) {
    __shared__ f16 qs[4096];
    __shared__ f16 ks[4096];
    __shared__ f16 vts[4096];       // V^T tile: [hd][key]
    __shared__ f16 attw[4][1024];   // per-wave P tile: [16 q][64 key]

    const int tid = threadIdx.x, lane = tid & 63, wv = tid >> 6;
    const int la = lane & 15, lg = lane >> 4;
    const int qt = blockIdx.x, bh = blockIdx.y;
    const f16* qh = q + (u64)bh * (S_ * 64) + qt * (64 * 64);
    const f16* kh = k + (u64)bh * (S_ * 64);
    const f16* vh = v + (u64)bh * (S_ * 64);

    const u32 f0 = tid * 8u, f1 = f0 + 2048u;
    const int r_0 = f0 >> 6, c_0 = f0 & 63;
    const int r_1 = f1 >> 6, c_1 = f1 & 63;

    {   // stage q tile once (visible after first barrier below)
        f16x8 v0 = *(const f16x8*)(qh + r_0 * 64 + c_0);
        f16x8 v1 = *(const f16x8*)(qh + r_1 * 64 + c_1);
        *(f16x8*)(qs + swz64(r_0, c_0 >> 3)) = v0;
        *(f16x8*)(qs + swz64(r_1, c_1 >> 3)) = v1;
    }

    const f32x4 VZ = {0.f, 0.f, 0.f, 0.f};
    float psum[4] = {0.f, 0.f, 0.f, 0.f};

    // ---- pass 1: row sums of exp(scores)
    for (int kt = 0; kt < 32; ++kt) {
        const f16* kb = kh + kt * 4096;
        f16x8 t0 = *(const f16x8*)(kb + r_0 * 64 + c_0);
        f16x8 t1 = *(const f16x8*)(kb + r_1 * 64 + c_1);
        __syncthreads();
        *(f16x8*)(ks + swz64(r_0, c_0 >> 3)) = t0;
        *(f16x8*)(ks + swz64(r_1, c_1 >> 3)) = t1;
        __syncthreads();
        f32x4 sc[4] = {VZ, VZ, VZ, VZ};
#pragma unroll
        for (int ch = 0; ch < 2; ++ch) {
            f16x8 af = *(const f16x8*)(qs + swz64(wv * 16 + la, ch * 4 + lg));
#pragma unroll
            for (int n = 0; n < 4; ++n) {
                f16x8 bf = *(const f16x8*)(ks + swz64(n * 16 + la, ch * 4 + lg));
                sc[n] = __builtin_amdgcn_mfma_f32_16x16x32_f16(af, bf, sc[n], 0, 0, 0);
            }
        }
#pragma unroll
        for (int n = 0; n < 4; ++n)
#pragma unroll
            for (int j = 0; j < 4; ++j) psum[j] += __expf(sc[n][j]);
    }

    float invl[4];
#pragma unroll
    for (int j = 0; j < 4; ++j) {
        float s = psum[j];
        s += __shfl_xor(s, 1);
        s += __shfl_xor(s, 2);
        s += __shfl_xor(s, 4);
        s += __shfl_xor(s, 8);
        invl[j] = 1.0f / s;
    }

    // ---- pass 2: recompute scores, write att, fuse PV
    f32x4 accy[4] = {VZ, VZ, VZ, VZ};
    for (int kt = 0; kt < 32; ++kt) {
        const f16* kb = kh + kt * 4096;
        const f16* vb = vh + kt * 4096;
        f16x8 t0 = *(const f16x8*)(kb + r_0 * 64 + c_0);
        f16x8 t1 = *(const f16x8*)(kb + r_1 * 64 + c_1);
        f16x8 u0 = *(const f16x8*)(vb + r_0 * 64 + c_0);
        f16x8 u1 = *(const f16x8*)(vb + r_1 * 64 + c_1);
        __syncthreads();
        *(f16x8*)(ks + swz64(r_0, c_0 >> 3)) = t0;
        *(f16x8*)(ks + swz64(r_1, c_1 >> 3)) = t1;
#pragma unroll
        for (int e = 0; e < 8; ++e) vts[swz64e(c_0 + e, r_0)] = u0[e];  // transpose V
#pragma unroll
        for (int e = 0; e < 8; ++e) vts[swz64e(c_1 + e, r_1)] = u1[e];
        __syncthreads();

        f32x4 sc[4] = {VZ, VZ, VZ, VZ};
#pragma unroll
        for (int ch = 0; ch < 2; ++ch) {
            f16x8 af = *(const f16x8*)(qs + swz64(wv * 16 + la, ch * 4 + lg));
#pragma unroll
            for (int n = 0; n < 4; ++n) {
                f16x8 bf = *(const f16x8*)(ks + swz64(n * 16 + la, ch * 4 + lg));
                sc[n] = __builtin_amdgcn_mfma_f32_16x16x32_f16(af, bf, sc[n], 0, 0, 0);
            }
        }
        float* ab = att + ((u64)bh * S_ + (u64)qt * 64 + wv * 16) * S_ + kt * 64;
#pragma unroll
        for (int n = 0; n < 4; ++n)
#pragma unroll
            for (int j = 0; j < 4; ++j) {
                float p = __expf(sc[n][j]) * invl[j];
                ab[(u64)(lg * 4 + j) * S_ + n * 16 + la] = p;
                attw[wv][swz64e(lg * 4 + j, n * 16 + la)] = (f16)p;
            }
        // PV: accy[q][hd] += P[q][key] * V[key][hd]
#pragma unroll
        for (int ch = 0; ch < 2; ++ch) {
            f16x8 pa = *(const f16x8*)(attw[wv] + swz64(la, ch * 4 + lg));
#pragma unroll
            for (int n = 0; n < 4; ++n) {
                f16x8 vf = *(const f16x8*)(vts + swz64(n * 16 + la, ch * 4 + lg));
                accy[n] = __builtin_amdgcn_mfma_f32_16x16x32_f16(pa, vf, accy[n], 0, 0, 0);
            }
        }
    }

    const int b = bh >> 4, h = bh & 15;
    f16* yb = ya + ((u64)b * S_ + qt * 64 + wv * 16) * D_ + h * 64;
#pragma unroll
    for (int n = 0; n < 4; ++n)
#pragma unroll
        for (int j = 0; j < 4; ++j)
            yb[(u64)(lg * 4 + j) * D_ + n * 16 + la] = (f16)accy[n][j];
}

// ---------------- launcher ----------------
extern "C" void kernel_launch(void* const* d_in, const int* in_sizes, int n_in,
                              void* d_out, int out_size, void* d_ws, size_t ws_size,
                              hipStream_t stream) {
    const float* x  = (const float*)d_in[0];
    const float* wa = (const float*)d_in[1];
    const float* wp = (const float*)d_in[2];
    const float* bp = (const float*)d_in[3];
    float* outY   = (float*)d_out;            // [2,2048,1024]
    float* outAtt = outY + 4194304ull;        // [2,16,2048,2048]

    char* ws = (char*)d_ws;                   // ~48 MB used
    f16* xb  = (f16*)(ws + 0);                // [4096][1024]
    f16* wab = (f16*)(ws + 8388608);          // [3072][1024]
    f16* wpb = (f16*)(ws + 14680064);         // [1024][1024]
    f16* qb  = (f16*)(ws + 16777216);         // [B][H][S][64] (pre-scaled 1/8)
    f16* kb  = (f16*)(ws + 25165824);         // [B][H][S][64]
    f16* vb  = (f16*)(ws + 33554432);         // [B][H][S][64]
    f16* yab = (f16*)(ws + 41943040);         // [4096][1024]

    convert_f16<<<4096, 256, 0, stream>>>(x, wa, wp, xb, wab, wpb);
    gemm_bt<0><<<dim3(32, 24), 256, 0, stream>>>(xb, wab, 1024, qb, kb, vb, nullptr, nullptr);
    attn_fused<<<dim3(32, 32), 256, 0, stream>>>(qb, kb, vb, outAtt, yab);
    gemm_bt<1><<<dim3(32, 8), 256, 0, stream>>>(yab, wpb, 1024, nullptr, nullptr, nullptr, outY, bp);
}